// Round 18
// baseline (822.089 us; speedup 1.0000x reference)
//
#include <hip/hip_runtime.h>
#include <stdint.h>

constexpr int SEQ  = 4096;
constexpr int HID  = 2048;
constexpr int NHEAD = 16;
constexpr int HDIM = 128;
constexpr int INTER = 5504;
constexpr int IPAD  = 5632;   // INTER padded to 256 multiple
constexpr int NHALF = 2816;   // MLP column half (44 tiles of 64)

using u16 = unsigned short;
typedef __bf16 bf16x8 __attribute__((ext_vector_type(8)));
typedef float  f32x4  __attribute__((ext_vector_type(4)));
typedef u16    u16x4  __attribute__((ext_vector_type(4)));
typedef u16    u16x8  __attribute__((ext_vector_type(8)));

__device__ __forceinline__ u16 f2bf(float f) {
  union { float f; unsigned u; } v; v.f = f;
  return (u16)((v.u + 0x7fffu + ((v.u >> 16) & 1u)) >> 16);  // RNE
}
__device__ __forceinline__ float bf2f(u16 u) {
  union { unsigned u; float f; } v; v.u = ((unsigned)u) << 16;
  return v.f;
}

// packed f32x2 -> bf16x2 (RNE), hw instruction; no builtin on gfx950
__device__ __forceinline__ unsigned cvtpk(float lo, float hi) {
  unsigned r;
  asm("v_cvt_pk_bf16_f32 %0, %1, %2" : "=v"(r) : "v"(lo), "v"(hi));
  return r;
}

// async global->LDS, 16B per lane. LDS dest = wave-uniform base + lane*16.
__device__ __forceinline__ void gl16(const u16* g, u16* l) {
  u16* gg = const_cast<u16*>(g);
  __builtin_amdgcn_global_load_lds(
      (__attribute__((address_space(1))) u16*)gg,
      (__attribute__((address_space(3))) u16*)l, 16, 0, 0);
}

__device__ __forceinline__ f32x4 mfma16(bf16x8 a, bf16x8 b, f32x4 c) {
  return __builtin_amdgcn_mfma_f32_16x16x32_bf16(a, b, c, 0, 0, 0);
}

// ---------------- diagnostic fill: encodes ws_size (MB) into d_out -------
__global__ __launch_bounds__(256)
void fill_k(float* __restrict__ o, float v, int n) {
  int i = blockIdx.x * 256 + threadIdx.x;
  if (i < n) o[i] = v;
}

// ---------------- RoPE cos/sin table: tbl[s*64+i] = (cos, sin) -----------
__global__ __launch_bounds__(256)
void ropetbl_k(float2* __restrict__ t) {
  const int idx = blockIdx.x * 256 + threadIdx.x;   // SEQ*64
  const int i = idx & 63, s = idx >> 6;
  const float inv_freq = exp2f(-(float)i * (13.287712379549449f / 64.0f));
  const float ang = (float)s * inv_freq;
  float sv, cv;
  sincosf(ang, &sv, &cv);
  t[idx] = make_float2(cv, sv);
}

// ---------------- RMSNorm: f32 (row) -> bf16, one block per row ----------
__global__ __launch_bounds__(256)
void rmsnorm_k(const float* __restrict__ x, const float* __restrict__ g,
               u16* __restrict__ o) {
  const int row = blockIdx.x, t = threadIdx.x;
  const float4* xr = (const float4*)(x + (size_t)row * HID);
  float4 a = xr[t * 2], b = xr[t * 2 + 1];
  float ss = a.x*a.x + a.y*a.y + a.z*a.z + a.w*a.w
           + b.x*b.x + b.y*b.y + b.z*b.z + b.w*b.w;
  #pragma unroll
  for (int m = 32; m; m >>= 1) ss += __shfl_xor(ss, m);
  __shared__ float red[4];
  if ((t & 63) == 0) red[t >> 6] = ss;
  __syncthreads();
  const float inv = rsqrtf((red[0]+red[1]+red[2]+red[3]) * (1.0f/HID) + 1e-6f);
  float vals[8] = {a.x,a.y,a.z,a.w,b.x,b.y,b.z,b.w};
  const int base = t * 8;
  u16x8 w;
  #pragma unroll
  for (int i = 0; i < 8; ++i) w[i] = f2bf(vals[i] * inv * g[base + i]);
  *(u16x8*)(o + (size_t)row * HID + base) = w;
}

// --- weight transpose+convert with zero-padding:
// in (Rin x Cin) f32, row stride ldin  ->  out (Cpad x Rpad) bf16, row stride ldout
// grid: (Cpad/32, Rpad/32). Blocks fully outside (Rin, Cin) write zeros.
__global__ __launch_bounds__(256)
void wtrans_k(const float* __restrict__ in, u16* __restrict__ out,
              int ldin, int ldout, int Rin, int Cin) {
  __shared__ float tile[32][33];
  const int cb = blockIdx.x * 32, rb = blockIdx.y * 32;
  const int t = threadIdx.x;
  const int c = t >> 3, r4 = (t & 7) * 4;
  if (rb >= Rin || cb >= Cin) {           // whole-block pad -> zeros
    u16x4 z = {0, 0, 0, 0};
    *(u16x4*)(out + (size_t)(cb + c) * ldout + rb + r4) = z;
    return;
  }
  const int r = t >> 3, c4 = (t & 7) * 4;
  float4 v = *(const float4*)(in + (size_t)(rb + r) * ldin + cb + c4);
  tile[r][c4] = v.x; tile[r][c4+1] = v.y; tile[r][c4+2] = v.z; tile[r][c4+3] = v.w;
  __syncthreads();
  u16x4 o;
  #pragma unroll
  for (int i = 0; i < 4; ++i) o[i] = f2bf(tile[r4 + i][c]);
  *(u16x4*)(out + (size_t)(cb + c) * ldout + rb + r4) = o;
}

// -------- V transpose per head: v (S,NH,HD) bf16 -> vt (NH,HD,S) bf16 ----
__global__ __launch_bounds__(256)
void vtrans_k(const u16* __restrict__ v, u16* __restrict__ vt) {
  __shared__ u16 tile[32][36];
  const int s0 = blockIdx.x * 32, d0 = blockIdx.y * 32, n = blockIdx.z;
  const int t = threadIdx.x;
  const int r = t >> 3, c4 = (t & 7) * 4;
  u16x4 in = *(const u16x4*)(v + (size_t)(s0 + r) * HID + n * HDIM + d0 + c4);
  tile[r][c4] = in[0]; tile[r][c4+1] = in[1]; tile[r][c4+2] = in[2]; tile[r][c4+3] = in[3];
  __syncthreads();
  const int d = t >> 3, s4 = (t & 7) * 4;
  u16x4 o;
  #pragma unroll
  for (int i = 0; i < 4; ++i) o[i] = tile[s4 + i][d];
  *(u16x4*)(vt + ((size_t)n * HDIM + d0 + d) * SEQ + s0 + s4) = o;
}

// ===== 128x128 bf16 MFMA GEMM, BK=64, 4 waves, 2-barrier flow =============
// r13-proven core. EPI 0 (QKV): col-split bf16 store with FUSED ROPE for
// q/k columns (r18): lanes l15 and l15^1 hold the (2i,2i+1) column pair of
// the same row; rotate in f32 from acc before the single bf16 rounding.
// extra = cos/sin table [SEQ][64] float2. V columns pass through.
// EPI 1: f32 = acc + extra (may alias C); EPI 2: silu; 3: plain bf16.
template<int EPI>
__global__ __launch_bounds__(256)
void gemm128(const u16* __restrict__ A, const u16* __restrict__ B,
             void* C, const void* extra, int M, int N, int K, int gx) {
  __shared__ __align__(16) u16 As[128 * 64];
  __shared__ __align__(16) u16 Bs[128 * 64];
  const int bid = blockIdx.x;
  const int cid = bid & 7;                   // XCD id (chunked dispatch)
  const int idx = bid >> 3;                  // index within XCD chunk
  const int grp = idx >> 4, win = idx & 15;  // 4x4 super-block
  const int bx = grp * 4 + (win & 3);
  const int by = cid * 4 + (win >> 2);
  (void)gx;
  const int m0 = by * 128, n0 = bx * 128;
  const int tid = threadIdx.x;
  const int w = tid >> 6, lane = tid & 63;
  const int l15 = lane & 15, g = lane >> 4;
  const int wr = w >> 1, wc = w & 1;
  const int NT = K >> 6;

  f32x4 acc[4][4] = {};

  const int srow = tid >> 3;                       // 0..31
  const int sgr  = ((tid & 7) ^ (srow & 7)) * 8;
  const u16* gA = A + (size_t)(m0 + srow) * K + sgr;
  const u16* gB = B + (size_t)(n0 + srow) * K + sgr;
  const size_t i32K = (size_t)32 * K;
  const int sl = w * 512;                          // wave slice within instr

  const int axor = l15 & 7;
  const int arow0 = (wr * 64 + l15) * 64;
  const int brow0 = (wc * 64 + l15) * 64;

  for (int T = 0; T < NT; ++T) {
    const size_t k0 = (size_t)T * 64;
    gl16(gA + k0,            As + 0 * 2048 + sl);
    gl16(gA + k0 +     i32K, As + 1 * 2048 + sl);
    gl16(gA + k0 + 2 * i32K, As + 2 * 2048 + sl);
    gl16(gA + k0 + 3 * i32K, As + 3 * 2048 + sl);
    gl16(gB + k0,            Bs + 0 * 2048 + sl);
    gl16(gB + k0 +     i32K, Bs + 1 * 2048 + sl);
    gl16(gB + k0 + 2 * i32K, Bs + 2 * 2048 + sl);
    gl16(gB + k0 + 3 * i32K, Bs + 3 * 2048 + sl);
    asm volatile("s_waitcnt vmcnt(0)" ::: "memory");   // LDS-DMA landed
    __syncthreads();
    #pragma unroll
    for (int ks = 0; ks < 2; ++ks) {
      const int aoff = ((ks * 4 + g) ^ axor) * 8;
      bf16x8 af[4], bfr[4];
      #pragma unroll
      for (int i = 0; i < 4; ++i)
        af[i] = *(const bf16x8*)&As[arow0 + i * 16 * 64 + aoff];
      #pragma unroll
      for (int j = 0; j < 4; ++j)
        bfr[j] = *(const bf16x8*)&Bs[brow0 + j * 16 * 64 + aoff];
      #pragma unroll
      for (int i = 0; i < 4; ++i)
        #pragma unroll
        for (int j = 0; j < 4; ++j)
          acc[i][j] = mfma16(af[i], bfr[j], acc[i][j]);
    }
    asm volatile("s_waitcnt lgkmcnt(0)" ::: "memory"); // ds_reads retired
    __syncthreads();
  }

  // ---- epilogue -----------------------------------------------------------
  #pragma unroll
  for (int i = 0; i < 4; ++i) {
    #pragma unroll
    for (int r = 0; r < 4; ++r) {
      const int row = m0 + wr * 64 + i * 16 + g * 4 + r;
      #pragma unroll
      for (int j = 0; j < 4; ++j) {
        const int col = n0 + wc * 64 + j * 16 + l15;
        const float v = acc[i][j][r];
        if constexpr (EPI == 0) {         // qkv split + fused rope on q/k
          float vr = v;
          const float vp = __shfl_xor(v, 1);   // partner column, same row
          if (col < 2 * HID) {                 // uniform per 16-lane group
            const float2 cs = ((const float2*)extra)
                [(size_t)row * 64 + ((col & 127) >> 1)];
            vr = (l15 & 1) ? (v * cs.x + vp * cs.y)
                           : (v * cs.x - vp * cs.y);
          }
          ((u16*)C)[(size_t)(col >> 11) * ((size_t)SEQ * HID)
                    + (size_t)row * HID + (col & 2047)] = f2bf(vr);
        } else if constexpr (EPI == 1) {  // f32 residual add (extra may alias C)
          const size_t idx2 = (size_t)row * N + col;
          ((float*)C)[idx2] = v + ((const float*)extra)[idx2];
        } else if constexpr (EPI == 2) {  // silu(acc) * extra, in-place safe
          const size_t idx2 = (size_t)row * N + col;
          const float upv = bf2f(((const u16*)extra)[idx2]);
          ((u16*)C)[idx2] = f2bf(v / (1.0f + __expf(-v)) * upv);
        } else {                          // plain bf16
          ((u16*)C)[(size_t)row * N + col] = f2bf(v);
        }
      }
    }
  }
}

// ===== 128x64 variant for N=2048 GEMMs (Wo, down-proj) ====================
// r14-proven: 1024 blocks (4/CU immediate), LDS 24KB. Same sync/swizzle/
// super-block map as gemm128.
template<int EPI>
__global__ __launch_bounds__(256)
void gemm128n64(const u16* __restrict__ A, const u16* __restrict__ B,
                void* C, const void* extra, int M, int N, int K, int gx) {
  __shared__ __align__(16) u16 As[128 * 64];
  __shared__ __align__(16) u16 Bs[64 * 64];
  const int bid = blockIdx.x;
  const int cid = bid & 7;
  const int idx = bid >> 3;
  const int grp = idx >> 4, win = idx & 15;
  const int bx = grp * 4 + (win & 3);        // 0..31 (N/64)
  const int by = cid * 4 + (win >> 2);       // 0..31 (M/128)
  (void)gx;
  const int m0 = by * 128, n0 = bx * 64;
  const int tid = threadIdx.x;
  const int w = tid >> 6, lane = tid & 63;
  const int l15 = lane & 15, g = lane >> 4;
  const int wr = w >> 1, wc = w & 1;
  const int NT = K >> 6;

  f32x4 acc[4][2] = {};

  const int srow = tid >> 3;                       // 0..31
  const int sgr  = ((tid & 7) ^ (srow & 7)) * 8;
  const u16* gA = A + (size_t)(m0 + srow) * K + sgr;
  const u16* gB = B + (size_t)(n0 + srow) * K + sgr;
  const size_t i32K = (size_t)32 * K;
  const int sl = w * 512;

  const int axor = l15 & 7;
  const int arow0 = (wr * 64 + l15) * 64;
  const int brow0 = (wc * 32 + l15) * 64;

  for (int T = 0; T < NT; ++T) {
    const size_t k0 = (size_t)T * 64;
    gl16(gA + k0,            As + 0 * 2048 + sl);
    gl16(gA + k0 +     i32K, As + 1 * 2048 + sl);
    gl16(gA + k0 + 2 * i32K, As + 2 * 2048 + sl);
    gl16(gA + k0 + 3 * i32K, As + 3 * 2048 + sl);
    gl16(gB + k0,            Bs + 0 * 2048 + sl);
    gl16(gB + k0 +     i32K, Bs + 1 * 2048 + sl);
    asm volatile("s_waitcnt vmcnt(0)" ::: "memory");   // LDS-DMA landed
    __syncthreads();
    #pragma unroll
    for (int ks = 0; ks < 2; ++ks) {
      const int aoff = ((ks * 4 + g) ^ axor) * 8;
      bf16x8 af[4], bfr[2];
      #pragma unroll
      for (int i = 0; i < 4; ++i)
        af[i] = *(const bf16x8*)&As[arow0 + i * 16 * 64 + aoff];
      #pragma unroll
      for (int j = 0; j < 2; ++j)
        bfr[j] = *(const bf16x8*)&Bs[brow0 + j * 16 * 64 + aoff];
      #pragma unroll
      for (int i = 0; i < 4; ++i)
        #pragma unroll
        for (int j = 0; j < 2; ++j)
          acc[i][j] = mfma16(af[i], bfr[j], acc[i][j]);
    }
    asm volatile("s_waitcnt lgkmcnt(0)" ::: "memory"); // ds_reads retired
    __syncthreads();
  }

  #pragma unroll
  for (int i = 0; i < 4; ++i) {
    #pragma unroll
    for (int r = 0; r < 4; ++r) {
      const int row = m0 + wr * 64 + i * 16 + g * 4 + r;
      #pragma unroll
      for (int j = 0; j < 2; ++j) {
        const int col = n0 + wc * 32 + j * 16 + l15;
        const float v = acc[i][j][r];
        if constexpr (EPI == 1) {         // f32 residual add (extra may alias C)
          const size_t idx2 = (size_t)row * N + col;
          ((float*)C)[idx2] = v + ((const float*)extra)[idx2];
        } else {                          // plain bf16
          ((u16*)C)[(size_t)row * N + col] = f2bf(v);
        }
      }
    }
  }
}

// ===== fused up/gate GEMM: C = silu(A@Bg^T) * (A@Bu^T), 128x64 tiles =====
// r15-proven: eliminates the 92MB uph round-trip. Dual-B staging, same
// sync/swizzle/super-block map. Grid 1408 (gx=44).
__global__ __launch_bounds__(256)
void gemm_ug(const u16* __restrict__ A, const u16* __restrict__ Bu,
             const u16* __restrict__ Bg, u16* C, int ldC, int K) {
  __shared__ __align__(16) u16 As[128 * 64];
  __shared__ __align__(16) u16 BsU[64 * 64];
  __shared__ __align__(16) u16 BsG[64 * 64];
  const int bid = blockIdx.x;
  const int cid = bid & 7;
  const int idx = bid >> 3;
  const int grp = idx >> 4, win = idx & 15;
  const int bx = grp * 4 + (win & 3);        // 0..43
  const int by = cid * 4 + (win >> 2);       // 0..31
  const int m0 = by * 128, n0 = bx * 64;
  const int tid = threadIdx.x;
  const int w = tid >> 6, lane = tid & 63;
  const int l15 = lane & 15, g = lane >> 4;
  const int wr = w >> 1, wc = w & 1;
  const int NT = K >> 6;

  f32x4 accU[4][2] = {};
  f32x4 accG[4][2] = {};

  const int srow = tid >> 3;                       // 0..31
  const int sgr  = ((tid & 7) ^ (srow & 7)) * 8;
  const u16* gA = A  + (size_t)(m0 + srow) * K + sgr;
  const u16* gU = Bu + (size_t)(n0 + srow) * K + sgr;
  const u16* gG = Bg + (size_t)(n0 + srow) * K + sgr;
  const size_t i32K = (size_t)32 * K;
  const int sl = w * 512;

  const int axor = l15 & 7;
  const int arow0 = (wr * 64 + l15) * 64;
  const int brow0 = (wc * 32 + l15) * 64;

  for (int T = 0; T < NT; ++T) {
    const size_t k0 = (size_t)T * 64;
    gl16(gA + k0,            As + 0 * 2048 + sl);
    gl16(gA + k0 +     i32K, As + 1 * 2048 + sl);
    gl16(gA + k0 + 2 * i32K, As + 2 * 2048 + sl);
    gl16(gA + k0 + 3 * i32K, As + 3 * 2048 + sl);
    gl16(gU + k0,            BsU + 0 * 2048 + sl);
    gl16(gU + k0 +     i32K, BsU + 1 * 2048 + sl);
    gl16(gG + k0,            BsG + 0 * 2048 + sl);
    gl16(gG + k0 +     i32K, BsG + 1 * 2048 + sl);
    asm volatile("s_waitcnt vmcnt(0)" ::: "memory");   // LDS-DMA landed
    __syncthreads();
    #pragma unroll
    for (int ks = 0; ks < 2; ++ks) {
      const int aoff = ((ks * 4 + g) ^ axor) * 8;
      bf16x8 af[4], bu[2], bg[2];
      #pragma unroll
      for (int i = 0; i < 4; ++i)
        af[i] = *(const bf16x8*)&As[arow0 + i * 16 * 64 + aoff];
      #pragma unroll
      for (int j = 0; j < 2; ++j) {
        bu[j] = *(const bf16x8*)&BsU[brow0 + j * 16 * 64 + aoff];
        bg[j] = *(const bf16x8*)&BsG[brow0 + j * 16 * 64 + aoff];
      }
      #pragma unroll
      for (int i = 0; i < 4; ++i)
        #pragma unroll
        for (int j = 0; j < 2; ++j) {
          accU[i][j] = mfma16(af[i], bu[j], accU[i][j]);
          accG[i][j] = mfma16(af[i], bg[j], accG[i][j]);
        }
    }
    asm volatile("s_waitcnt lgkmcnt(0)" ::: "memory"); // ds_reads retired
    __syncthreads();
  }

  #pragma unroll
  for (int i = 0; i < 4; ++i) {
    #pragma unroll
    for (int r = 0; r < 4; ++r) {
      const int row = m0 + wr * 64 + i * 16 + g * 4 + r;
      #pragma unroll
      for (int j = 0; j < 2; ++j) {
        const int col = n0 + wc * 32 + j * 16 + l15;
        const float up = accU[i][j][r];
        const float gt = accG[i][j][r];
        C[(size_t)row * ldC + col] = f2bf(gt / (1.0f + __expf(-gt)) * up);
      }
    }
  }
}

// ------------- Flash attention (causal), 4 waves x 16 q-rows, KVBLK=64 ---
// r15-proven best (heavy-first + XCD map): diag-split mask, defer-max,
// ones-MFMA row sums, cvt_pk, setprio around MFMA clusters, explicit
// counter drains. Byte-identical to r17.
__global__ __launch_bounds__(256)
void attn_k(const u16* __restrict__ q, const u16* __restrict__ k,
            const u16* __restrict__ vt, u16* __restrict__ o) {
  __shared__ __align__(16) u16 Ks[64 * 128];   // [t][d], rows 256B, swizzled
  __shared__ __align__(16) u16 Vs[128 * 64];   // [d][t], rows 128B, swizzled
  __shared__ __align__(16) u16 Ps[4 * 16 * 64];// per-wave [q][t], swizzled
  const int b = blockIdx.x;
  const int n    = ((b & 7) << 1) | ((b >> 3) & 1);  // 2 heads per XCD
  const int qIdx = 63 - (b >> 4);                    // heavy tiles first
  const int q0   = qIdx * 64;
  const int tid = threadIdx.x;
  const int wave = tid >> 6, lane = tid & 63;
  const int l15 = lane & 15, g = lane >> 4;

  bf16x8 aq[4];
  {
    const u16* qp = q + (size_t)(q0 + wave*16 + l15) * HID + n * HDIM + g * 8;
    #pragma unroll
    for (int d = 0; d < 4; ++d) aq[d] = *(const bf16x8*)(qp + d * 32);
  }
  float mrow[4];
  #pragma unroll
  for (int r = 0; r < 4; ++r) mrow[r] = -__builtin_inff();
  f32x4 oacc[8] = {};
  f32x4 lacc = {0.0f, 0.0f, 0.0f, 0.0f};            // row sums via ones-MFMA
  const bf16x8 vone = {(__bf16)1.0f, (__bf16)1.0f, (__bf16)1.0f, (__bf16)1.0f,
                       (__bf16)1.0f, (__bf16)1.0f, (__bf16)1.0f, (__bf16)1.0f};

  const int kRow = tid >> 4;
  const int kCs  = (tid & 15) ^ (kRow & 7);
  const u16* kg = k + (size_t)kRow * HID + n * HDIM + kCs * 8;
  const int vRow = tid >> 3;
  const int vCs  = (tid & 7) ^ (vRow & 7);
  const u16* vg = vt + ((size_t)n * HDIM + vRow) * SEQ + vCs * 8;

  u16* PW = Ps + wave * 1024;
  const int rsw = (l15 & 7) << 3;
  const float C = 0.12751744f;                      // log2(e)/sqrt(128)

  const int nt = qIdx + 1;
  for (int it = 0; it < nt; ++it) {
    const int t0 = it * 64;
    #pragma unroll
    for (int s = 0; s < 4; ++s)
      gl16(kg + (size_t)(t0 + s*16) * HID, Ks + s*2048 + wave*512);
    #pragma unroll
    for (int s = 0; s < 4; ++s)
      gl16(vg + (size_t)(s*32) * SEQ + t0, Vs + s*2048 + wave*512);
    asm volatile("s_waitcnt vmcnt(0)" ::: "memory");
    __syncthreads();

    f32x4 sc[4] = {};
    __builtin_amdgcn_s_setprio(1);
    #pragma unroll
    for (int tb = 0; tb < 4; ++tb) {
      #pragma unroll
      for (int dd = 0; dd < 4; ++dd) {
        bf16x8 bk = *(const bf16x8*)(Ks + (tb*16 + l15)*128 + ((dd*32 + g*8) ^ rsw));
        sc[tb] = mfma16(aq[dd], bk, sc[tb]);
      }
    }
    __builtin_amdgcn_s_setprio(0);

    const bool diag = (it == qIdx);                 // uniform branch
    #pragma unroll
    for (int r = 0; r < 4; ++r) {
      float v0 = sc[0][r], v1 = sc[1][r], v2 = sc[2][r], v3 = sc[3][r];
      if (diag) {
        const int srow = q0 + wave*16 + g*4 + r;
        const int tt = t0 + l15;
        if (tt      > srow) v0 = -__builtin_inff();
        if (tt + 16 > srow) v1 = -__builtin_inff();
        if (tt + 32 > srow) v2 = -__builtin_inff();
        if (tt + 48 > srow) v3 = -__builtin_inff();
      }
      float mx = fmaxf(fmaxf(v0, v1), fmaxf(v2, v3));
      mx = fmaxf(mx, __shfl_xor(mx, 1));
      mx = fmaxf(mx, __shfl_xor(mx, 2));
      mx = fmaxf(mx, __shfl_xor(mx, 4));
      mx = fmaxf(mx, __shfl_xor(mx, 8));
      if (mx > mrow[r] + 60.0f) {                   // defer-max rescale
        const float f = exp2f((mrow[r] - mx) * C);
        mrow[r] = mx;
        lacc[r] *= f;
        #pragma unroll
        for (int db = 0; db < 8; ++db) oacc[db][r] *= f;
      }
      const float m = mrow[r];
      const float p0 = exp2f((v0 - m) * C);
      const float p1 = exp2f((v1 - m) * C);
      const float p2 = exp2f((v2 - m) * C);
      const float p3 = exp2f((v3 - m) * C);
      const unsigned pk01 = cvtpk(p0, p1);
      const unsigned pk23 = cvtpk(p2, p3);
      const int prow = g*4 + r;
      const int psw = (prow & 7) << 3;
      PW[prow*64 + ( l15        ^ psw)] = (u16)pk01;
      PW[prow*64 + ((16 + l15)  ^ psw)] = (u16)(pk01 >> 16);
      PW[prow*64 + ((32 + l15)  ^ psw)] = (u16)pk23;
      PW[prow*64 + ((48 + l15)  ^ psw)] = (u16)(pk23 >> 16);
    }

    bf16x8 ap0 = *(const bf16x8*)(PW + l15*64 + ((g*8)      ^ rsw));
    bf16x8 ap1 = *(const bf16x8*)(PW + l15*64 + ((32 + g*8) ^ rsw));
    __builtin_amdgcn_s_setprio(1);
    lacc = mfma16(ap0, vone, lacc);                 // row-sum accumulation
    lacc = mfma16(ap1, vone, lacc);
    #pragma unroll
    for (int db = 0; db < 8; ++db) {
      bf16x8 bv0 = *(const bf16x8*)(Vs + (db*16 + l15)*64 + ((g*8)      ^ rsw));
      bf16x8 bv1 = *(const bf16x8*)(Vs + (db*16 + l15)*64 + ((32 + g*8) ^ rsw));
      oacc[db] = mfma16(ap0, bv0, oacc[db]);
      oacc[db] = mfma16(ap1, bv1, oacc[db]);
    }
    __builtin_amdgcn_s_setprio(0);
    asm volatile("s_waitcnt lgkmcnt(0)" ::: "memory");
    __syncthreads();
  }

  #pragma unroll
  for (int db = 0; db < 8; ++db) {
    #pragma unroll
    for (int r = 0; r < 4; ++r) {
      const int srow = q0 + wave*16 + g*4 + r;
      o[(size_t)srow * HID + n * HDIM + db*16 + l15] = f2bf(oacc[db][r] / lacc[r]);
    }
  }
}

// ---------------------------------------------------------------------------
extern "C" void kernel_launch(void* const* d_in, const int* in_sizes, int n_in,
                              void* d_out, int out_size, void* d_ws, size_t ws_size,
                              hipStream_t stream) {
  (void)in_sizes; (void)n_in; (void)out_size;
  const float* x  = (const float*)d_in[0];
  const float* wq = (const float*)d_in[1];
  const float* wk = (const float*)d_in[2];
  const float* wv = (const float*)d_in[3];
  const float* wo = (const float*)d_in[4];
  const float* wg = (const float*)d_in[5];
  const float* wu = (const float*)d_in[6];
  const float* wd = (const float*)d_in[7];
  const float* g1 = (const float*)d_in[8];
  const float* g2 = (const float*)d_in[9];
  float* out = (float*)d_out;

  // ---- arena (bytes), liveness-overlaid -----------------------------------
  constexpr size_t HB  = (size_t)SEQ * HID * 2;       // 16,777,216
  constexpr size_t WT  = (size_t)HID * HID * 2;       //  8,388,608
  constexpr size_t WUP = (size_t)IPAD * HID * 2;      // 23,068,672
  constexpr size_t WHF = (size_t)NHALF * HID * 2;     // 11,534,336
  constexpr size_t MB_ = (size_t)SEQ * IPAD * 2;      // 46,137,344
  constexpr size_t TBL = (size_t)SEQ * 64 * 8;        //  2,097,152
  constexpr size_t NEED1 = 4 * HB + 3 * WT + TBL;     // 94,371,840 (phase 1)
  constexpr size_t NEED2 = HB + 2 * WHF + MB_;        // 85,983,232 (phase 2)
  constexpr size_t NEED = NEED1 > NEED2 ? NEED1 : NEED2;
  static_assert(WUP <= 2 * WHF, "wdT fits weight slot");

  if (ws_size < NEED) {  // diagnostic: encode ws_size (MB) into the output
    const int n = SEQ * HID;
    fill_k<<<dim3((n + 255) / 256), 256, 0, stream>>>(out, (float)(ws_size >> 20), n);
    return;
  }

  char* base = (char*)d_ws;
  // phase 1
  u16* h1     = (u16*)(base);
  u16* wqkvT  = (u16*)(base + HB);            // q|k|v transposed, 3*WT
  u16* qb     = (u16*)(base + HB + 3 * WT);   // q|k|v outputs, contiguous
  u16* kb     = (u16*)(base + 2 * HB + 3 * WT);
  u16* vb     = (u16*)(base + 3 * HB + 3 * WT);
  float2* tbl = (float2*)(base + 4 * HB + 3 * WT);   // rope cos/sin table
  u16* vtb    = h1;                            // h1 dead after QKV gemm
  u16* ob     = vb;                            // vb dead after vtrans
  u16* woT    = wqkvT;                         // wqkvT dead after QKV gemm
  // phase 2
  u16* h2    = (u16*)(base);
  u16* wuTh  = (u16*)(base + HB);              // weight slot (2*WHF total)
  u16* wgTh  = (u16*)(base + HB + WHF);
  u16* wdT   = wuTh;                           // reuses slot after halves
  u16* mb    = (u16*)(base + HB + 2 * WHF);    // fused silu*up output (MB_)

  // ---- phase 1: attention --------------------------------------------------
  ropetbl_k<<<dim3(SEQ * 64 / 256), 256, 0, stream>>>(tbl);

  wtrans_k<<<dim3(64, 64), 256, 0, stream>>>(wq, wqkvT,            HID, HID, HID, HID);
  wtrans_k<<<dim3(64, 64), 256, 0, stream>>>(wk, wqkvT + HID*HID,  HID, HID, HID, HID);
  wtrans_k<<<dim3(64, 64), 256, 0, stream>>>(wv, wqkvT + 2*HID*HID,HID, HID, HID, HID);

  rmsnorm_k<<<dim3(SEQ), 256, 0, stream>>>(x, g1, h1);

  // fused QKV + rope: (4096 x 6144) = h1 @ [wq|wk|wv]^T, rope on q/k cols
  gemm128<0><<<dim3(1536), 256, 0, stream>>>(h1, wqkvT, qb, tbl, SEQ, 3*HID, HID, 48);

  vtrans_k<<<dim3(SEQ/32, HDIM/32, NHEAD), 256, 0, stream>>>(vb, vtb);

  wtrans_k<<<dim3(64, 64), 256, 0, stream>>>(wo, woT, HID, HID, HID, HID);

  attn_k<<<dim3(SEQ/64 * NHEAD), 256, 0, stream>>>(qb, kb, vtb, ob);

  // x2 = x + attn @ wo  (f32, into d_out) — 128x64 tiles, 1024 blocks
  gemm128n64<1><<<dim3(1024), 256, 0, stream>>>(ob, woT, out, x, SEQ, HID, HID, 32);

  // ---- phase 2: MLP, fused up/gate in two N-halves --------------------------
  rmsnorm_k<<<dim3(SEQ), 256, 0, stream>>>(out, g2, h2);

  for (int h = 0; h < 2; ++h) {
    const int noff = h * NHALF;
    const int cin  = INTER - noff;             // 2816 real (h0) / 2688 (h1)
    wtrans_k<<<dim3(NHALF/32, 64), 256, 0, stream>>>(wu + noff, wuTh, INTER, HID, HID, cin);
    wtrans_k<<<dim3(NHALF/32, 64), 256, 0, stream>>>(wg + noff, wgTh, INTER, HID, HID, cin);
    // mb[:, noff:noff+2816] = silu(h2@wgTh^T) * (h2@wuTh^T)
    gemm_ug<<<dim3(1408), 256, 0, stream>>>(h2, wuTh, wgTh, mb + noff, IPAD, HID);
  }

  // out += mb @ wd^T  (wd transposed with zero pad cols; K = 5632) — 128x64
  wtrans_k<<<dim3(64, IPAD/32), 256, 0, stream>>>(wd, wdT, HID, IPAD, INTER, HID);
  gemm128n64<1><<<dim3(1024), 256, 0, stream>>>(mb, wdT, out, out, SEQ, HID, IPAD, 32);
}

// Round 19
// 796.212 us; speedup vs baseline: 1.0325x; 1.0325x over previous
//
#include <hip/hip_runtime.h>
#include <stdint.h>

constexpr int SEQ  = 4096;
constexpr int HID  = 2048;
constexpr int NHEAD = 16;
constexpr int HDIM = 128;
constexpr int INTER = 5504;
constexpr int IPAD  = 5632;   // INTER padded to 256 multiple
constexpr int NHALF = 2816;   // MLP column half (44 tiles of 64)

using u16 = unsigned short;
typedef __bf16 bf16x8 __attribute__((ext_vector_type(8)));
typedef float  f32x4  __attribute__((ext_vector_type(4)));
typedef u16    u16x4  __attribute__((ext_vector_type(4)));
typedef u16    u16x8  __attribute__((ext_vector_type(8)));

__device__ __forceinline__ u16 f2bf(float f) {
  union { float f; unsigned u; } v; v.f = f;
  return (u16)((v.u + 0x7fffu + ((v.u >> 16) & 1u)) >> 16);  // RNE
}
__device__ __forceinline__ float bf2f(u16 u) {
  union { unsigned u; float f; } v; v.u = ((unsigned)u) << 16;
  return v.f;
}

// packed f32x2 -> bf16x2 (RNE), hw instruction; no builtin on gfx950
__device__ __forceinline__ unsigned cvtpk(float lo, float hi) {
  unsigned r;
  asm("v_cvt_pk_bf16_f32 %0, %1, %2" : "=v"(r) : "v"(lo), "v"(hi));
  return r;
}

// async global->LDS, 16B per lane. LDS dest = wave-uniform base + lane*16.
__device__ __forceinline__ void gl16(const u16* g, u16* l) {
  u16* gg = const_cast<u16*>(g);
  __builtin_amdgcn_global_load_lds(
      (__attribute__((address_space(1))) u16*)gg,
      (__attribute__((address_space(3))) u16*)l, 16, 0, 0);
}

__device__ __forceinline__ f32x4 mfma16(bf16x8 a, bf16x8 b, f32x4 c) {
  return __builtin_amdgcn_mfma_f32_16x16x32_bf16(a, b, c, 0, 0, 0);
}

// ---------------- diagnostic fill: encodes ws_size (MB) into d_out -------
__global__ __launch_bounds__(256)
void fill_k(float* __restrict__ o, float v, int n) {
  int i = blockIdx.x * 256 + threadIdx.x;
  if (i < n) o[i] = v;
}

// ---------------- RMSNorm: f32 (row) -> bf16, one block per row ----------
__global__ __launch_bounds__(256)
void rmsnorm_k(const float* __restrict__ x, const float* __restrict__ g,
               u16* __restrict__ o) {
  const int row = blockIdx.x, t = threadIdx.x;
  const float4* xr = (const float4*)(x + (size_t)row * HID);
  float4 a = xr[t * 2], b = xr[t * 2 + 1];
  float ss = a.x*a.x + a.y*a.y + a.z*a.z + a.w*a.w
           + b.x*b.x + b.y*b.y + b.z*b.z + b.w*b.w;
  #pragma unroll
  for (int m = 32; m; m >>= 1) ss += __shfl_xor(ss, m);
  __shared__ float red[4];
  if ((t & 63) == 0) red[t >> 6] = ss;
  __syncthreads();
  const float inv = rsqrtf((red[0]+red[1]+red[2]+red[3]) * (1.0f/HID) + 1e-6f);
  float vals[8] = {a.x,a.y,a.z,a.w,b.x,b.y,b.z,b.w};
  const int base = t * 8;
  u16x8 w;
  #pragma unroll
  for (int i = 0; i < 8; ++i) w[i] = f2bf(vals[i] * inv * g[base + i]);
  *(u16x8*)(o + (size_t)row * HID + base) = w;
}

// --- weight transpose+convert with zero-padding:
// in (Rin x Cin) f32, row stride ldin  ->  out (Cpad x Rpad) bf16, row stride ldout
// grid: (Cpad/32, Rpad/32). Blocks fully outside (Rin, Cin) write zeros.
__global__ __launch_bounds__(256)
void wtrans_k(const float* __restrict__ in, u16* __restrict__ out,
              int ldin, int ldout, int Rin, int Cin) {
  __shared__ float tile[32][33];
  const int cb = blockIdx.x * 32, rb = blockIdx.y * 32;
  const int t = threadIdx.x;
  const int c = t >> 3, r4 = (t & 7) * 4;
  if (rb >= Rin || cb >= Cin) {           // whole-block pad -> zeros
    u16x4 z = {0, 0, 0, 0};
    *(u16x4*)(out + (size_t)(cb + c) * ldout + rb + r4) = z;
    return;
  }
  const int r = t >> 3, c4 = (t & 7) * 4;
  float4 v = *(const float4*)(in + (size_t)(rb + r) * ldin + cb + c4);
  tile[r][c4] = v.x; tile[r][c4+1] = v.y; tile[r][c4+2] = v.z; tile[r][c4+3] = v.w;
  __syncthreads();
  u16x4 o;
  #pragma unroll
  for (int i = 0; i < 4; ++i) o[i] = f2bf(tile[r4 + i][c]);
  *(u16x4*)(out + (size_t)(cb + c) * ldout + rb + r4) = o;
}

// -------- V transpose per head: v (S,NH,HD) bf16 -> vt (NH,HD,S) bf16 ----
__global__ __launch_bounds__(256)
void vtrans_k(const u16* __restrict__ v, u16* __restrict__ vt) {
  __shared__ u16 tile[32][36];
  const int s0 = blockIdx.x * 32, d0 = blockIdx.y * 32, n = blockIdx.z;
  const int t = threadIdx.x;
  const int r = t >> 3, c4 = (t & 7) * 4;
  u16x4 in = *(const u16x4*)(v + (size_t)(s0 + r) * HID + n * HDIM + d0 + c4);
  tile[r][c4] = in[0]; tile[r][c4+1] = in[1]; tile[r][c4+2] = in[2]; tile[r][c4+3] = in[3];
  __syncthreads();
  const int d = t >> 3, s4 = (t & 7) * 4;
  u16x4 o;
  #pragma unroll
  for (int i = 0; i < 4; ++i) o[i] = tile[s4 + i][d];
  *(u16x4*)(vt + ((size_t)n * HDIM + d0 + d) * SEQ + s0 + s4) = o;
}

// ------------- RoPE in-place on (S,NH,HD) bf16 ---------------------------
__global__ __launch_bounds__(256)
void rope_k(u16* __restrict__ x) {
  const int idx = blockIdx.x * 256 + threadIdx.x;   // total SEQ*NHEAD*64
  const int i  = idx & 63;
  const int sn = idx >> 6;
  const int s  = sn >> 4;                            // NHEAD == 16
  const size_t base = (size_t)sn * HDIM + 2 * i;
  const float xe = bf2f(x[base]), xo = bf2f(x[base + 1]);
  const float inv_freq = exp2f(-(float)i * (13.287712379549449f / 64.0f));
  const float ang = (float)s * inv_freq;
  float sv, cv;
  sincosf(ang, &sv, &cv);
  x[base]     = f2bf(xe * cv - xo * sv);
  x[base + 1] = f2bf(xe * sv + xo * cv);
}

// ===== 128x128 bf16 MFMA GEMM, BK=64, 4 waves, 2-barrier flow =============
// r13-proven: explicit counter drains, zero-conflict swizzle, 4x4
// super-block XCD map (L2 panel reuse). Used for QKV (6 blocks/CU).
// r18's fused-rope epilogue was falsified (per-element shfl + table gather
// in the epilogue cost ~30us vs ~11us saved) — reverted to plain EPI 0.
// EPI 0: qkv col-split bf16; 1: f32 = acc + extra (may alias C);
// EPI 2: bf16 = silu(acc)*extra_bf16 (may alias C); 3: plain bf16.
template<int EPI>
__global__ __launch_bounds__(256)
void gemm128(const u16* __restrict__ A, const u16* __restrict__ B,
             void* C, const void* extra, int M, int N, int K, int gx) {
  __shared__ __align__(16) u16 As[128 * 64];
  __shared__ __align__(16) u16 Bs[128 * 64];
  const int bid = blockIdx.x;
  const int cid = bid & 7;                   // XCD id (chunked dispatch)
  const int idx = bid >> 3;                  // index within XCD chunk
  const int grp = idx >> 4, win = idx & 15;  // 4x4 super-block
  const int bx = grp * 4 + (win & 3);
  const int by = cid * 4 + (win >> 2);
  (void)gx;
  const int m0 = by * 128, n0 = bx * 128;
  const int tid = threadIdx.x;
  const int w = tid >> 6, lane = tid & 63;
  const int l15 = lane & 15, g = lane >> 4;
  const int wr = w >> 1, wc = w & 1;
  const int NT = K >> 6;

  f32x4 acc[4][4] = {};

  const int srow = tid >> 3;                       // 0..31
  const int sgr  = ((tid & 7) ^ (srow & 7)) * 8;
  const u16* gA = A + (size_t)(m0 + srow) * K + sgr;
  const u16* gB = B + (size_t)(n0 + srow) * K + sgr;
  const size_t i32K = (size_t)32 * K;
  const int sl = w * 512;                          // wave slice within instr

  const int axor = l15 & 7;
  const int arow0 = (wr * 64 + l15) * 64;
  const int brow0 = (wc * 64 + l15) * 64;

  for (int T = 0; T < NT; ++T) {
    const size_t k0 = (size_t)T * 64;
    gl16(gA + k0,            As + 0 * 2048 + sl);
    gl16(gA + k0 +     i32K, As + 1 * 2048 + sl);
    gl16(gA + k0 + 2 * i32K, As + 2 * 2048 + sl);
    gl16(gA + k0 + 3 * i32K, As + 3 * 2048 + sl);
    gl16(gB + k0,            Bs + 0 * 2048 + sl);
    gl16(gB + k0 +     i32K, Bs + 1 * 2048 + sl);
    gl16(gB + k0 + 2 * i32K, Bs + 2 * 2048 + sl);
    gl16(gB + k0 + 3 * i32K, Bs + 3 * 2048 + sl);
    asm volatile("s_waitcnt vmcnt(0)" ::: "memory");   // LDS-DMA landed
    __syncthreads();
    #pragma unroll
    for (int ks = 0; ks < 2; ++ks) {
      const int aoff = ((ks * 4 + g) ^ axor) * 8;
      bf16x8 af[4], bfr[4];
      #pragma unroll
      for (int i = 0; i < 4; ++i)
        af[i] = *(const bf16x8*)&As[arow0 + i * 16 * 64 + aoff];
      #pragma unroll
      for (int j = 0; j < 4; ++j)
        bfr[j] = *(const bf16x8*)&Bs[brow0 + j * 16 * 64 + aoff];
      #pragma unroll
      for (int i = 0; i < 4; ++i)
        #pragma unroll
        for (int j = 0; j < 4; ++j)
          acc[i][j] = mfma16(af[i], bfr[j], acc[i][j]);
    }
    asm volatile("s_waitcnt lgkmcnt(0)" ::: "memory"); // ds_reads retired
    __syncthreads();
  }

  // ---- epilogue -----------------------------------------------------------
  #pragma unroll
  for (int i = 0; i < 4; ++i) {
    #pragma unroll
    for (int r = 0; r < 4; ++r) {
      const int row = m0 + wr * 64 + i * 16 + g * 4 + r;
      #pragma unroll
      for (int j = 0; j < 4; ++j) {
        const int col = n0 + wc * 64 + j * 16 + l15;
        const float v = acc[i][j][r];
        if constexpr (EPI == 0) {         // qkv split (q|k|v contiguous HBs)
          ((u16*)C)[(size_t)(col >> 11) * ((size_t)SEQ * HID)
                    + (size_t)row * HID + (col & 2047)] = f2bf(v);
        } else if constexpr (EPI == 1) {  // f32 residual add (extra may alias C)
          const size_t idx2 = (size_t)row * N + col;
          ((float*)C)[idx2] = v + ((const float*)extra)[idx2];
        } else if constexpr (EPI == 2) {  // silu(acc) * extra, in-place safe
          const size_t idx2 = (size_t)row * N + col;
          const float upv = bf2f(((const u16*)extra)[idx2]);
          ((u16*)C)[idx2] = f2bf(v / (1.0f + __expf(-v)) * upv);
        } else {                          // plain bf16
          ((u16*)C)[(size_t)row * N + col] = f2bf(v);
        }
      }
    }
  }
}

// ===== 128x64 variant for N=2048 GEMMs (Wo, down-proj) ====================
// r14-proven: 1024 blocks (4/CU immediate), LDS 24KB. Same sync/swizzle/
// super-block map as gemm128.
template<int EPI>
__global__ __launch_bounds__(256)
void gemm128n64(const u16* __restrict__ A, const u16* __restrict__ B,
                void* C, const void* extra, int M, int N, int K, int gx) {
  __shared__ __align__(16) u16 As[128 * 64];
  __shared__ __align__(16) u16 Bs[64 * 64];
  const int bid = blockIdx.x;
  const int cid = bid & 7;
  const int idx = bid >> 3;
  const int grp = idx >> 4, win = idx & 15;
  const int bx = grp * 4 + (win & 3);        // 0..31 (N/64)
  const int by = cid * 4 + (win >> 2);       // 0..31 (M/128)
  (void)gx;
  const int m0 = by * 128, n0 = bx * 64;
  const int tid = threadIdx.x;
  const int w = tid >> 6, lane = tid & 63;
  const int l15 = lane & 15, g = lane >> 4;
  const int wr = w >> 1, wc = w & 1;
  const int NT = K >> 6;

  f32x4 acc[4][2] = {};

  const int srow = tid >> 3;                       // 0..31
  const int sgr  = ((tid & 7) ^ (srow & 7)) * 8;
  const u16* gA = A + (size_t)(m0 + srow) * K + sgr;
  const u16* gB = B + (size_t)(n0 + srow) * K + sgr;
  const size_t i32K = (size_t)32 * K;
  const int sl = w * 512;

  const int axor = l15 & 7;
  const int arow0 = (wr * 64 + l15) * 64;
  const int brow0 = (wc * 32 + l15) * 64;

  for (int T = 0; T < NT; ++T) {
    const size_t k0 = (size_t)T * 64;
    gl16(gA + k0,            As + 0 * 2048 + sl);
    gl16(gA + k0 +     i32K, As + 1 * 2048 + sl);
    gl16(gA + k0 + 2 * i32K, As + 2 * 2048 + sl);
    gl16(gA + k0 + 3 * i32K, As + 3 * 2048 + sl);
    gl16(gB + k0,            Bs + 0 * 2048 + sl);
    gl16(gB + k0 +     i32K, Bs + 1 * 2048 + sl);
    asm volatile("s_waitcnt vmcnt(0)" ::: "memory");   // LDS-DMA landed
    __syncthreads();
    #pragma unroll
    for (int ks = 0; ks < 2; ++ks) {
      const int aoff = ((ks * 4 + g) ^ axor) * 8;
      bf16x8 af[4], bfr[2];
      #pragma unroll
      for (int i = 0; i < 4; ++i)
        af[i] = *(const bf16x8*)&As[arow0 + i * 16 * 64 + aoff];
      #pragma unroll
      for (int j = 0; j < 2; ++j)
        bfr[j] = *(const bf16x8*)&Bs[brow0 + j * 16 * 64 + aoff];
      #pragma unroll
      for (int i = 0; i < 4; ++i)
        #pragma unroll
        for (int j = 0; j < 2; ++j)
          acc[i][j] = mfma16(af[i], bfr[j], acc[i][j]);
    }
    asm volatile("s_waitcnt lgkmcnt(0)" ::: "memory"); // ds_reads retired
    __syncthreads();
  }

  #pragma unroll
  for (int i = 0; i < 4; ++i) {
    #pragma unroll
    for (int r = 0; r < 4; ++r) {
      const int row = m0 + wr * 64 + i * 16 + g * 4 + r;
      #pragma unroll
      for (int j = 0; j < 2; ++j) {
        const int col = n0 + wc * 32 + j * 16 + l15;
        const float v = acc[i][j][r];
        if constexpr (EPI == 1) {         // f32 residual add (extra may alias C)
          const size_t idx2 = (size_t)row * N + col;
          ((float*)C)[idx2] = v + ((const float*)extra)[idx2];
        } else {                          // plain bf16
          ((u16*)C)[(size_t)row * N + col] = f2bf(v);
        }
      }
    }
  }
}

// ===== fused up/gate GEMM: C = silu(A@Bg^T) * (A@Bu^T), 128x64 tiles =====
// r15-proven: eliminates the 92MB uph round-trip. Dual-B staging, same
// sync/swizzle/super-block map. Grid 1408 (gx=44).
__global__ __launch_bounds__(256)
void gemm_ug(const u16* __restrict__ A, const u16* __restrict__ Bu,
             const u16* __restrict__ Bg, u16* C, int ldC, int K) {
  __shared__ __align__(16) u16 As[128 * 64];
  __shared__ __align__(16) u16 BsU[64 * 64];
  __shared__ __align__(16) u16 BsG[64 * 64];
  const int bid = blockIdx.x;
  const int cid = bid & 7;
  const int idx = bid >> 3;
  const int grp = idx >> 4, win = idx & 15;
  const int bx = grp * 4 + (win & 3);        // 0..43
  const int by = cid * 4 + (win >> 2);       // 0..31
  const int m0 = by * 128, n0 = bx * 64;
  const int tid = threadIdx.x;
  const int w = tid >> 6, lane = tid & 63;
  const int l15 = lane & 15, g = lane >> 4;
  const int wr = w >> 1, wc = w & 1;
  const int NT = K >> 6;

  f32x4 accU[4][2] = {};
  f32x4 accG[4][2] = {};

  const int srow = tid >> 3;                       // 0..31
  const int sgr  = ((tid & 7) ^ (srow & 7)) * 8;
  const u16* gA = A  + (size_t)(m0 + srow) * K + sgr;
  const u16* gU = Bu + (size_t)(n0 + srow) * K + sgr;
  const u16* gG = Bg + (size_t)(n0 + srow) * K + sgr;
  const size_t i32K = (size_t)32 * K;
  const int sl = w * 512;

  const int axor = l15 & 7;
  const int arow0 = (wr * 64 + l15) * 64;
  const int brow0 = (wc * 32 + l15) * 64;

  for (int T = 0; T < NT; ++T) {
    const size_t k0 = (size_t)T * 64;
    gl16(gA + k0,            As + 0 * 2048 + sl);
    gl16(gA + k0 +     i32K, As + 1 * 2048 + sl);
    gl16(gA + k0 + 2 * i32K, As + 2 * 2048 + sl);
    gl16(gA + k0 + 3 * i32K, As + 3 * 2048 + sl);
    gl16(gU + k0,            BsU + 0 * 2048 + sl);
    gl16(gU + k0 +     i32K, BsU + 1 * 2048 + sl);
    gl16(gG + k0,            BsG + 0 * 2048 + sl);
    gl16(gG + k0 +     i32K, BsG + 1 * 2048 + sl);
    asm volatile("s_waitcnt vmcnt(0)" ::: "memory");   // LDS-DMA landed
    __syncthreads();
    #pragma unroll
    for (int ks = 0; ks < 2; ++ks) {
      const int aoff = ((ks * 4 + g) ^ axor) * 8;
      bf16x8 af[4], bu[2], bg[2];
      #pragma unroll
      for (int i = 0; i < 4; ++i)
        af[i] = *(const bf16x8*)&As[arow0 + i * 16 * 64 + aoff];
      #pragma unroll
      for (int j = 0; j < 2; ++j) {
        bu[j] = *(const bf16x8*)&BsU[brow0 + j * 16 * 64 + aoff];
        bg[j] = *(const bf16x8*)&BsG[brow0 + j * 16 * 64 + aoff];
      }
      #pragma unroll
      for (int i = 0; i < 4; ++i)
        #pragma unroll
        for (int j = 0; j < 2; ++j) {
          accU[i][j] = mfma16(af[i], bu[j], accU[i][j]);
          accG[i][j] = mfma16(af[i], bg[j], accG[i][j]);
        }
    }
    asm volatile("s_waitcnt lgkmcnt(0)" ::: "memory"); // ds_reads retired
    __syncthreads();
  }

  #pragma unroll
  for (int i = 0; i < 4; ++i) {
    #pragma unroll
    for (int r = 0; r < 4; ++r) {
      const int row = m0 + wr * 64 + i * 16 + g * 4 + r;
      #pragma unroll
      for (int j = 0; j < 2; ++j) {
        const int col = n0 + wc * 32 + j * 16 + l15;
        const float up = accU[i][j][r];
        const float gt = accG[i][j][r];
        C[(size_t)row * ldC + col] = f2bf(gt / (1.0f + __expf(-gt)) * up);
      }
    }
  }
}

// ------------- Flash attention (causal), 4 waves x 16 q-rows, KVBLK=64 ---
// r15-proven best (heavy-first + XCD map): diag-split mask, defer-max,
// ones-MFMA row sums, cvt_pk, setprio around MFMA clusters, explicit
// counter drains. Byte-identical to r17.
__global__ __launch_bounds__(256)
void attn_k(const u16* __restrict__ q, const u16* __restrict__ k,
            const u16* __restrict__ vt, u16* __restrict__ o) {
  __shared__ __align__(16) u16 Ks[64 * 128];   // [t][d], rows 256B, swizzled
  __shared__ __align__(16) u16 Vs[128 * 64];   // [d][t], rows 128B, swizzled
  __shared__ __align__(16) u16 Ps[4 * 16 * 64];// per-wave [q][t], swizzled
  const int b = blockIdx.x;
  const int n    = ((b & 7) << 1) | ((b >> 3) & 1);  // 2 heads per XCD
  const int qIdx = 63 - (b >> 4);                    // heavy tiles first
  const int q0   = qIdx * 64;
  const int tid = threadIdx.x;
  const int wave = tid >> 6, lane = tid & 63;
  const int l15 = lane & 15, g = lane >> 4;

  bf16x8 aq[4];
  {
    const u16* qp = q + (size_t)(q0 + wave*16 + l15) * HID + n * HDIM + g * 8;
    #pragma unroll
    for (int d = 0; d < 4; ++d) aq[d] = *(const bf16x8*)(qp + d * 32);
  }
  float mrow[4];
  #pragma unroll
  for (int r = 0; r < 4; ++r) mrow[r] = -__builtin_inff();
  f32x4 oacc[8] = {};
  f32x4 lacc = {0.0f, 0.0f, 0.0f, 0.0f};            // row sums via ones-MFMA
  const bf16x8 vone = {(__bf16)1.0f, (__bf16)1.0f, (__bf16)1.0f, (__bf16)1.0f,
                       (__bf16)1.0f, (__bf16)1.0f, (__bf16)1.0f, (__bf16)1.0f};

  const int kRow = tid >> 4;
  const int kCs  = (tid & 15) ^ (kRow & 7);
  const u16* kg = k + (size_t)kRow * HID + n * HDIM + kCs * 8;
  const int vRow = tid >> 3;
  const int vCs  = (tid & 7) ^ (vRow & 7);
  const u16* vg = vt + ((size_t)n * HDIM + vRow) * SEQ + vCs * 8;

  u16* PW = Ps + wave * 1024;
  const int rsw = (l15 & 7) << 3;
  const float C = 0.12751744f;                      // log2(e)/sqrt(128)

  const int nt = qIdx + 1;
  for (int it = 0; it < nt; ++it) {
    const int t0 = it * 64;
    #pragma unroll
    for (int s = 0; s < 4; ++s)
      gl16(kg + (size_t)(t0 + s*16) * HID, Ks + s*2048 + wave*512);
    #pragma unroll
    for (int s = 0; s < 4; ++s)
      gl16(vg + (size_t)(s*32) * SEQ + t0, Vs + s*2048 + wave*512);
    asm volatile("s_waitcnt vmcnt(0)" ::: "memory");
    __syncthreads();

    f32x4 sc[4] = {};
    __builtin_amdgcn_s_setprio(1);
    #pragma unroll
    for (int tb = 0; tb < 4; ++tb) {
      #pragma unroll
      for (int dd = 0; dd < 4; ++dd) {
        bf16x8 bk = *(const bf16x8*)(Ks + (tb*16 + l15)*128 + ((dd*32 + g*8) ^ rsw));
        sc[tb] = mfma16(aq[dd], bk, sc[tb]);
      }
    }
    __builtin_amdgcn_s_setprio(0);

    const bool diag = (it == qIdx);                 // uniform branch
    #pragma unroll
    for (int r = 0; r < 4; ++r) {
      float v0 = sc[0][r], v1 = sc[1][r], v2 = sc[2][r], v3 = sc[3][r];
      if (diag) {
        const int srow = q0 + wave*16 + g*4 + r;
        const int tt = t0 + l15;
        if (tt      > srow) v0 = -__builtin_inff();
        if (tt + 16 > srow) v1 = -__builtin_inff();
        if (tt + 32 > srow) v2 = -__builtin_inff();
        if (tt + 48 > srow) v3 = -__builtin_inff();
      }
      float mx = fmaxf(fmaxf(v0, v1), fmaxf(v2, v3));
      mx = fmaxf(mx, __shfl_xor(mx, 1));
      mx = fmaxf(mx, __shfl_xor(mx, 2));
      mx = fmaxf(mx, __shfl_xor(mx, 4));
      mx = fmaxf(mx, __shfl_xor(mx, 8));
      if (mx > mrow[r] + 60.0f) {                   // defer-max rescale
        const float f = exp2f((mrow[r] - mx) * C);
        mrow[r] = mx;
        lacc[r] *= f;
        #pragma unroll
        for (int db = 0; db < 8; ++db) oacc[db][r] *= f;
      }
      const float m = mrow[r];
      const float p0 = exp2f((v0 - m) * C);
      const float p1 = exp2f((v1 - m) * C);
      const float p2 = exp2f((v2 - m) * C);
      const float p3 = exp2f((v3 - m) * C);
      const unsigned pk01 = cvtpk(p0, p1);
      const unsigned pk23 = cvtpk(p2, p3);
      const int prow = g*4 + r;
      const int psw = (prow & 7) << 3;
      PW[prow*64 + ( l15        ^ psw)] = (u16)pk01;
      PW[prow*64 + ((16 + l15)  ^ psw)] = (u16)(pk01 >> 16);
      PW[prow*64 + ((32 + l15)  ^ psw)] = (u16)pk23;
      PW[prow*64 + ((48 + l15)  ^ psw)] = (u16)(pk23 >> 16);
    }

    bf16x8 ap0 = *(const bf16x8*)(PW + l15*64 + ((g*8)      ^ rsw));
    bf16x8 ap1 = *(const bf16x8*)(PW + l15*64 + ((32 + g*8) ^ rsw));
    __builtin_amdgcn_s_setprio(1);
    lacc = mfma16(ap0, vone, lacc);                 // row-sum accumulation
    lacc = mfma16(ap1, vone, lacc);
    #pragma unroll
    for (int db = 0; db < 8; ++db) {
      bf16x8 bv0 = *(const bf16x8*)(Vs + (db*16 + l15)*64 + ((g*8)      ^ rsw));
      bf16x8 bv1 = *(const bf16x8*)(Vs + (db*16 + l15)*64 + ((32 + g*8) ^ rsw));
      oacc[db] = mfma16(ap0, bv0, oacc[db]);
      oacc[db] = mfma16(ap1, bv1, oacc[db]);
    }
    __builtin_amdgcn_s_setprio(0);
    asm volatile("s_waitcnt lgkmcnt(0)" ::: "memory");
    __syncthreads();
  }

  #pragma unroll
  for (int db = 0; db < 8; ++db) {
    #pragma unroll
    for (int r = 0; r < 4; ++r) {
      const int srow = q0 + wave*16 + g*4 + r;
      o[(size_t)srow * HID + n * HDIM + db*16 + l15] = f2bf(oacc[db][r] / lacc[r]);
    }
  }
}

// ---------------------------------------------------------------------------
extern "C" void kernel_launch(void* const* d_in, const int* in_sizes, int n_in,
                              void* d_out, int out_size, void* d_ws, size_t ws_size,
                              hipStream_t stream) {
  (void)in_sizes; (void)n_in; (void)out_size;
  const float* x  = (const float*)d_in[0];
  const float* wq = (const float*)d_in[1];
  const float* wk = (const float*)d_in[2];
  const float* wv = (const float*)d_in[3];
  const float* wo = (const float*)d_in[4];
  const float* wg = (const float*)d_in[5];
  const float* wu = (const float*)d_in[6];
  const float* wd = (const float*)d_in[7];
  const float* g1 = (const float*)d_in[8];
  const float* g2 = (const float*)d_in[9];
  float* out = (float*)d_out;

  // ---- arena (bytes), liveness-overlaid -----------------------------------
  constexpr size_t HB  = (size_t)SEQ * HID * 2;       // 16,777,216
  constexpr size_t WT  = (size_t)HID * HID * 2;       //  8,388,608
  constexpr size_t WUP = (size_t)IPAD * HID * 2;      // 23,068,672
  constexpr size_t WHF = (size_t)NHALF * HID * 2;     // 11,534,336
  constexpr size_t MB_ = (size_t)SEQ * IPAD * 2;      // 46,137,344
  constexpr size_t NEED1 = 4 * HB + 3 * WT;           // 92,274,688 (phase 1)
  constexpr size_t NEED2 = HB + 2 * WHF + MB_;        // 85,983,232 (phase 2)
  constexpr size_t NEED = NEED1 > NEED2 ? NEED1 : NEED2;
  static_assert(WUP <= 2 * WHF, "wdT fits weight slot");

  if (ws_size < NEED) {  // diagnostic: encode ws_size (MB) into the output
    const int n = SEQ * HID;
    fill_k<<<dim3((n + 255) / 256), 256, 0, stream>>>(out, (float)(ws_size >> 20), n);
    return;
  }

  char* base = (char*)d_ws;
  // phase 1
  u16* h1     = (u16*)(base);
  u16* wqkvT  = (u16*)(base + HB);            // q|k|v transposed, 3*WT
  u16* qb     = (u16*)(base + HB + 3 * WT);   // q|k|v outputs, contiguous
  u16* kb     = (u16*)(base + 2 * HB + 3 * WT);
  u16* vb     = (u16*)(base + 3 * HB + 3 * WT);
  u16* vtb    = h1;                            // h1 dead after QKV gemm
  u16* ob     = vb;                            // vb dead after vtrans
  u16* woT    = wqkvT;                         // wqkvT dead after QKV gemm
  // phase 2
  u16* h2    = (u16*)(base);
  u16* wuTh  = (u16*)(base + HB);              // weight slot (2*WHF total)
  u16* wgTh  = (u16*)(base + HB + WHF);
  u16* wdT   = wuTh;                           // reuses slot after halves
  u16* mb    = (u16*)(base + HB + 2 * WHF);    // fused silu*up output (MB_)

  // ---- phase 1: attention --------------------------------------------------
  wtrans_k<<<dim3(64, 64), 256, 0, stream>>>(wq, wqkvT,            HID, HID, HID, HID);
  wtrans_k<<<dim3(64, 64), 256, 0, stream>>>(wk, wqkvT + HID*HID,  HID, HID, HID, HID);
  wtrans_k<<<dim3(64, 64), 256, 0, stream>>>(wv, wqkvT + 2*HID*HID,HID, HID, HID, HID);

  rmsnorm_k<<<dim3(SEQ), 256, 0, stream>>>(x, g1, h1);

  // fused QKV: (4096 x 6144) = h1 @ [wq|wk|wv]^T, split epilogue
  gemm128<0><<<dim3(1536), 256, 0, stream>>>(h1, wqkvT, qb, nullptr, SEQ, 3*HID, HID, 48);

  rope_k<<<dim3(SEQ * NHEAD * 64 / 256), 256, 0, stream>>>(qb);
  rope_k<<<dim3(SEQ * NHEAD * 64 / 256), 256, 0, stream>>>(kb);

  vtrans_k<<<dim3(SEQ/32, HDIM/32, NHEAD), 256, 0, stream>>>(vb, vtb);

  wtrans_k<<<dim3(64, 64), 256, 0, stream>>>(wo, woT, HID, HID, HID, HID);

  attn_k<<<dim3(SEQ/64 * NHEAD), 256, 0, stream>>>(qb, kb, vtb, ob);

  // x2 = x + attn @ wo  (f32, into d_out) — 128x64 tiles, 1024 blocks
  gemm128n64<1><<<dim3(1024), 256, 0, stream>>>(ob, woT, out, x, SEQ, HID, HID, 32);

  // ---- phase 2: MLP, fused up/gate in two N-halves --------------------------
  rmsnorm_k<<<dim3(SEQ), 256, 0, stream>>>(out, g2, h2);

  for (int h = 0; h < 2; ++h) {
    const int noff = h * NHALF;
    const int cin  = INTER - noff;             // 2816 real (h0) / 2688 (h1)
    wtrans_k<<<dim3(NHALF/32, 64), 256, 0, stream>>>(wu + noff, wuTh, INTER, HID, HID, cin);
    wtrans_k<<<dim3(NHALF/32, 64), 256, 0, stream>>>(wg + noff, wgTh, INTER, HID, HID, cin);
    // mb[:, noff:noff+2816] = silu(h2@wgTh^T) * (h2@wuTh^T)
    gemm_ug<<<dim3(1408), 256, 0, stream>>>(h2, wuTh, wgTh, mb + noff, IPAD, HID);
  }

  // out += mb @ wd^T  (wd transposed with zero pad cols; K = 5632) — 128x64
  wtrans_k<<<dim3(64, IPAD/32), 256, 0, stream>>>(wd, wdT, HID, IPAD, INTER, HID);
  gemm128n64<1><<<dim3(1024), 256, 0, stream>>>(mb, wdT, out, out, SEQ, HID, IPAD, 32);
}